// Round 1
// baseline (2716.677 us; speedup 1.0000x reference)
//
#include <hip/hip_runtime.h>

#define NN 200000
#define EE (NN - 1)
#define D 50
#define NSTEPS 4
#define DTC 0.01f

__device__ __forceinline__ float swishf(float x) {
    return x / (1.0f + __expf(-x));
}

// edge encoder: scalar edge value -> 16-dim latent
__device__ __forceinline__ void edge_enc(float ev,
                                         const float* __restrict__ w1,
                                         const float* __restrict__ b1,
                                         const float* __restrict__ w2,
                                         const float* __restrict__ b2,
                                         float* outv) {
    float h[16];
#pragma unroll
    for (int j = 0; j < 16; ++j) h[j] = swishf(fmaf(ev, w1[j], b1[j]));
#pragma unroll
    for (int j = 0; j < 16; ++j) {
        float s = b2[j];
#pragma unroll
        for (int k = 0; k < 16; ++k) s = fmaf(h[k], w2[k * 16 + j], s);
        outv[j] = s;
    }
}

__global__ __launch_bounds__(256, 2)
void gnode_main(const float* __restrict__ nodes,
                const float* __restrict__ edges,
                const float* __restrict__ g,
                const float* __restrict__ enc_n_w1, const float* __restrict__ enc_n_b1,
                const float* __restrict__ enc_n_w2, const float* __restrict__ enc_n_b2,
                const float* __restrict__ enc_e_w1, const float* __restrict__ enc_e_b1,
                const float* __restrict__ enc_e_w2, const float* __restrict__ enc_e_b2,
                const float* __restrict__ ode_w1, const float* __restrict__ ode_b1,
                const float* __restrict__ ode_w2, const float* __restrict__ ode_b2,
                const float* __restrict__ node_out_w, const float* __restrict__ node_out_b,
                const float* __restrict__ dec_n_w1, const float* __restrict__ dec_n_b1,
                const float* __restrict__ dec_n_w2, const float* __restrict__ dec_n_b2,
                const float* __restrict__ dec_n_w3, const float* __restrict__ dec_n_b3,
                float* __restrict__ out)
{
    const int i = blockIdx.x * blockDim.x + threadIdx.x;
    if (i >= NN) return;

    // ---- load node features ----
    float nf[5];
#pragma unroll
    for (int c = 0; c < 5; ++c) nf[c] = nodes[i * 5 + c];

    // ---- node encoder: swish(nodes@W1+b1)@W2+b2 ----
    float h16[16];
#pragma unroll
    for (int j = 0; j < 16; ++j) h16[j] = enc_n_b1[j];
#pragma unroll
    for (int c = 0; c < 5; ++c)
#pragma unroll
        for (int j = 0; j < 16; ++j)
            h16[j] = fmaf(nf[c], enc_n_w1[c * 16 + j], h16[j]);
#pragma unroll
    for (int j = 0; j < 16; ++j) h16[j] = swishf(h16[j]);

    float y[D];
#pragma unroll
    for (int j = 0; j < 16; ++j) {
        float s = enc_n_b2[j];
#pragma unroll
        for (int k = 0; k < 16; ++k) s = fmaf(h16[k], enc_n_w2[k * 16 + j], s);
        y[j] = s;
    }

    // ---- edge latents: sent = elat[i] (i<E), recv = elat[i-1] (i>0) ----
    if (i < EE) {
        edge_enc(edges[i], enc_e_w1, enc_e_b1, enc_e_w2, enc_e_b2, &y[16]);
    } else {
#pragma unroll
        for (int j = 0; j < 16; ++j) y[16 + j] = 0.0f;
    }
    if (i > 0) {
        edge_enc(edges[i - 1], enc_e_w1, enc_e_b1, enc_e_w2, enc_e_b2, &y[32]);
    } else {
#pragma unroll
        for (int j = 0; j < 16; ++j) y[32 + j] = 0.0f;
    }
    y[48] = g[0];
    y[49] = g[1];

    // ---- RK4 integration of dy/dt = relu([y,t]@W1+b1)@W2+b2 ----
    const float hh = 1.0f / NSTEPS;
    float t = 0.0f;
    float acc[D], arg[D], hidd[D];

#pragma clang loop unroll(disable)
    for (int step = 0; step < NSTEPS; ++step) {
#pragma unroll
        for (int j = 0; j < D; ++j) { acc[j] = y[j]; arg[j] = y[j]; }

#pragma clang loop unroll(disable)
        for (int s = 0; s < 4; ++s) {
            const float ts = (s == 0) ? 0.0f : ((s == 3) ? hh : 0.5f * hh);
            const float ca = (s == 0 || s == 3) ? hh / 6.0f : hh / 3.0f;
            const float cb = (s == 2) ? hh : 0.5f * hh;
            const float tcur = t + ts;

            // hidden = relu(arg @ W1[0:50] + tcur*W1[50] + b1)
#pragma unroll
            for (int j = 0; j < D; ++j)
                hidd[j] = fmaf(tcur, ode_w1[50 * D + j], ode_b1[j]);
#pragma unroll
            for (int ii = 0; ii < D; ++ii)
#pragma unroll
                for (int j = 0; j < D; ++j)
                    hidd[j] = fmaf(arg[ii], ode_w1[ii * D + j], hidd[j]);
#pragma unroll
            for (int j = 0; j < D; ++j) hidd[j] = fmaxf(hidd[j], 0.0f);

            // k = hidd @ W2 + b2  (accumulated into arg, which is dead now)
#pragma unroll
            for (int j = 0; j < D; ++j) arg[j] = ode_b2[j];
#pragma unroll
            for (int kk = 0; kk < D; ++kk)
#pragma unroll
                for (int j = 0; j < D; ++j)
                    arg[j] = fmaf(hidd[kk], ode_w2[kk * D + j], arg[j]);

            // acc += ca*k ; arg = y + cb*k (next stage input; harmless at s==3)
#pragma unroll
            for (int j = 0; j < D; ++j) {
                const float kv = arg[j];
                acc[j] = fmaf(ca, kv, acc[j]);
                arg[j] = fmaf(cb, kv, y[j]);
            }
        }
#pragma unroll
        for (int j = 0; j < D; ++j) y[j] = acc[j];
        t += hh;
    }

    // ---- decoder ----
    float n2[16];
#pragma unroll
    for (int j = 0; j < 16; ++j) n2[j] = node_out_b[j];
#pragma unroll
    for (int kk = 0; kk < D; ++kk)
#pragma unroll
        for (int j = 0; j < 16; ++j)
            n2[j] = fmaf(y[kk], node_out_w[kk * 16 + j], n2[j]);

    float dh[16];
#pragma unroll
    for (int j = 0; j < 16; ++j) dh[j] = dec_n_b1[j];
#pragma unroll
    for (int kk = 0; kk < 16; ++kk)
#pragma unroll
        for (int j = 0; j < 16; ++j)
            dh[j] = fmaf(n2[kk], dec_n_w1[kk * 16 + j], dh[j]);
#pragma unroll
    for (int j = 0; j < 16; ++j) dh[j] = swishf(dh[j]);

    float dh2[16];
#pragma unroll
    for (int j = 0; j < 16; ++j) dh2[j] = dec_n_b2[j];
#pragma unroll
    for (int kk = 0; kk < 16; ++kk)
#pragma unroll
        for (int j = 0; j < 16; ++j)
            dh2[j] = fmaf(dh[kk], dec_n_w2[kk * 16 + j], dh2[j]);
#pragma unroll
    for (int j = 0; j < 16; ++j) dh2[j] = swishf(dh2[j]);

    float pred = dec_n_b3[0];
#pragma unroll
    for (int kk = 0; kk < 16; ++kk) pred = fmaf(dh2[kk], dec_n_w3[kk], pred);

    const float cur_pos = nf[0];
    const float cur_vel = nf[4];
    const float next_vel = fmaf(pred, DTC, cur_vel);
    const float next_pos = fmaf(next_vel, DTC, cur_pos);

    out[i * 6 + 0] = next_pos;
    out[i * 6 + 1] = nf[2];
    out[i * 6 + 2] = nf[3];
    out[i * 6 + 3] = nf[4];
    out[i * 6 + 4] = next_vel;
    out[i * 6 + 5] = pred;
}

// second pass: next_edges = diff(next_pos) read back from d_out, plus g_new
__global__ void gnode_edges(const float* __restrict__ out_nodes,
                            float* __restrict__ out,
                            const float* __restrict__ g)
{
    const int e = blockIdx.x * blockDim.x + threadIdx.x;
    if (e < EE) {
        out[NN * 6 + e] = out_nodes[(e + 1) * 6] - out_nodes[e * 6];
    }
    if (e == 0) {
        out[NN * 6 + EE]     = g[0] + 1.0f;
        out[NN * 6 + EE + 1] = g[1];
    }
}

extern "C" void kernel_launch(void* const* d_in, const int* in_sizes, int n_in,
                              void* d_out, int out_size, void* d_ws, size_t ws_size,
                              hipStream_t stream) {
    const float* nodes     = (const float*)d_in[0];
    const float* edges     = (const float*)d_in[1];
    const float* g         = (const float*)d_in[2];
    const float* enc_n_w1  = (const float*)d_in[3];
    const float* enc_n_b1  = (const float*)d_in[4];
    const float* enc_n_w2  = (const float*)d_in[5];
    const float* enc_n_b2  = (const float*)d_in[6];
    const float* enc_e_w1  = (const float*)d_in[7];
    const float* enc_e_b1  = (const float*)d_in[8];
    const float* enc_e_w2  = (const float*)d_in[9];
    const float* enc_e_b2  = (const float*)d_in[10];
    const float* ode_w1    = (const float*)d_in[11];
    const float* ode_b1    = (const float*)d_in[12];
    const float* ode_w2    = (const float*)d_in[13];
    const float* ode_b2    = (const float*)d_in[14];
    const float* node_out_w = (const float*)d_in[15];
    const float* node_out_b = (const float*)d_in[16];
    const float* dec_n_w1  = (const float*)d_in[17];
    const float* dec_n_b1  = (const float*)d_in[18];
    const float* dec_n_w2  = (const float*)d_in[19];
    const float* dec_n_b2  = (const float*)d_in[20];
    const float* dec_n_w3  = (const float*)d_in[21];
    const float* dec_n_b3  = (const float*)d_in[22];
    float* out = (float*)d_out;

    const int threads = 256;
    const int blocks = (NN + threads - 1) / threads;
    gnode_main<<<blocks, threads, 0, stream>>>(
        nodes, edges, g,
        enc_n_w1, enc_n_b1, enc_n_w2, enc_n_b2,
        enc_e_w1, enc_e_b1, enc_e_w2, enc_e_b2,
        ode_w1, ode_b1, ode_w2, ode_b2,
        node_out_w, node_out_b,
        dec_n_w1, dec_n_b1, dec_n_w2, dec_n_b2, dec_n_w3, dec_n_b3,
        out);

    gnode_edges<<<(EE + 255) / 256, 256, 0, stream>>>(out, out, g);
}

// Round 3
// 2031.738 us; speedup vs baseline: 1.3371x; 1.3371x over previous
//
#include <hip/hip_runtime.h>

#define NN 200000
#define EE (NN - 1)
#define D 50
#define H 25                 // half of D, columns per thread
#define NPB 128              // nodes per block (256 threads = 2 col-halves)
#define NSTEPS 4
#define DTC 0.01f

__device__ __forceinline__ float swishf(float x) {
    return x / (1.0f + __expf(-x));
}

// edge encoder: scalar edge value -> full 16-dim latent
__device__ __forceinline__ void edge_enc(float ev,
                                         const float* __restrict__ w1,
                                         const float* __restrict__ b1,
                                         const float* __restrict__ w2,
                                         const float* __restrict__ b2,
                                         float* outv) {
    float h[16];
#pragma unroll
    for (int j = 0; j < 16; ++j) h[j] = swishf(fmaf(ev, w1[j], b1[j]));
#pragma unroll
    for (int j = 0; j < 16; ++j) {
        float s = b2[j];
#pragma unroll
        for (int k = 0; k < 16; ++k) s = fmaf(h[k], w2[k * 16 + j], s);
        outv[j] = s;
    }
}

// Two waves per 64 nodes: waves 0-1 own columns 0-24, waves 2-3 own 25-49.
// Per-thread live state = 100 floats -> fits 128 VGPR, no scratch spills
// (R1 at 128 VGPR with 200-float state spilled ~450 MB).
__global__ __launch_bounds__(256, 2)
void gnode_main(const float* __restrict__ nodes,
                const float* __restrict__ edges,
                const float* __restrict__ g,
                const float* __restrict__ enc_n_w1, const float* __restrict__ enc_n_b1,
                const float* __restrict__ enc_n_w2, const float* __restrict__ enc_n_b2,
                const float* __restrict__ enc_e_w1, const float* __restrict__ enc_e_b1,
                const float* __restrict__ enc_e_w2, const float* __restrict__ enc_e_b2,
                const float* __restrict__ ode_w1, const float* __restrict__ ode_b1,
                const float* __restrict__ ode_w2, const float* __restrict__ ode_b2,
                const float* __restrict__ node_out_w, const float* __restrict__ node_out_b,
                const float* __restrict__ dec_n_w1, const float* __restrict__ dec_n_b1,
                const float* __restrict__ dec_n_w2, const float* __restrict__ dec_n_b2,
                const float* __restrict__ dec_n_w3, const float* __restrict__ dec_n_b3,
                float* __restrict__ out)
{
    // [row][node] layout: lanes index consecutive nodes -> stride-1 LDS,
    // 2 lanes/bank (free, m136). 50*128*4 = 25.6 KB.
    __shared__ float xbuf[D][NPB];

    const int tid = threadIdx.x;
    const int node_local = tid & (NPB - 1);
    // wave-uniform in fact; readfirstlane forces the compiler to see it,
    // keeping weight indices on the scalar (s_load) path.
    const int colSel = __builtin_amdgcn_readfirstlane(tid >> 7);
    const int colBase = colSel * H;
    const int i0 = blockIdx.x * NPB + node_local;
    const int i = (i0 < NN) ? i0 : (NN - 1);   // clamp tail; all threads barrier
    const bool active = (i0 < NN);

    float y[H];

    // ---------------- encoder ----------------
    if (colSel == 0) {
        // cols 0..15 = nlat, cols 16..24 = sent[0..8]
        float nf[5];
#pragma unroll
        for (int c = 0; c < 5; ++c) nf[c] = nodes[i * 5 + c];
        float h16[16];
#pragma unroll
        for (int j = 0; j < 16; ++j) h16[j] = enc_n_b1[j];
#pragma unroll
        for (int c = 0; c < 5; ++c)
#pragma unroll
            for (int j = 0; j < 16; ++j)
                h16[j] = fmaf(nf[c], enc_n_w1[c * 16 + j], h16[j]);
#pragma unroll
        for (int j = 0; j < 16; ++j) h16[j] = swishf(h16[j]);
#pragma unroll
        for (int j = 0; j < 16; ++j) {
            float s = enc_n_b2[j];
#pragma unroll
            for (int k = 0; k < 16; ++k) s = fmaf(h16[k], enc_n_w2[k * 16 + j], s);
            y[j] = s;
        }
        float els[16];
        if (i < EE) {
            edge_enc(edges[i], enc_e_w1, enc_e_b1, enc_e_w2, enc_e_b2, els);
        } else {
#pragma unroll
            for (int j = 0; j < 16; ++j) els[j] = 0.0f;
        }
#pragma unroll
        for (int jj = 16; jj < 25; ++jj) y[jj] = els[jj - 16];
    } else {
        // cols 25..31 = sent[9..15], 32..47 = recv[0..15], 48..49 = g
        float els[16], elr[16];
        if (i < EE) {
            edge_enc(edges[i], enc_e_w1, enc_e_b1, enc_e_w2, enc_e_b2, els);
        } else {
#pragma unroll
            for (int j = 0; j < 16; ++j) els[j] = 0.0f;
        }
        if (i > 0) {
            edge_enc(edges[i - 1], enc_e_w1, enc_e_b1, enc_e_w2, enc_e_b2, elr);
        } else {
#pragma unroll
            for (int j = 0; j < 16; ++j) elr[j] = 0.0f;
        }
#pragma unroll
        for (int jj = 0; jj < 7; ++jj) y[jj] = els[jj + 9];
#pragma unroll
        for (int jj = 7; jj < 23; ++jj) y[jj] = elr[jj - 7];
        y[23] = g[0];
        y[24] = g[1];
    }

    // ---------------- RK4 ----------------
    const float hh = 1.0f / NSTEPS;
    float t = 0.0f;
    float acc[H], arg[H], hidd[H];

#pragma clang loop unroll(disable)
    for (int step = 0; step < NSTEPS; ++step) {
#pragma unroll
        for (int jj = 0; jj < H; ++jj) { acc[jj] = y[jj]; arg[jj] = y[jj]; }

#pragma clang loop unroll(disable)
        for (int s = 0; s < 4; ++s) {
            const float ts = (s == 0) ? 0.0f : ((s == 3) ? hh : 0.5f * hh);
            const float ca = (s == 0 || s == 3) ? hh / 6.0f : hh / 3.0f;
            const float cb = (s == 2) ? hh : 0.5f * hh;
            const float tcur = t + ts;

            // publish arg halves
            __syncthreads();            // previous reads of xbuf are done
#pragma unroll
            for (int jj = 0; jj < H; ++jj) xbuf[colBase + jj][node_local] = arg[jj];
            __syncthreads();

            // hidd = relu(full_arg @ W1[:50] + tcur*W1[50] + b1), my 25 cols
#pragma unroll
            for (int jj = 0; jj < H; ++jj)
                hidd[jj] = fmaf(tcur, ode_w1[50 * D + colBase + jj], ode_b1[colBase + jj]);
#pragma unroll
            for (int kk = 0; kk < D; ++kk) {
                const float xv = xbuf[kk][node_local];
#pragma unroll
                for (int jj = 0; jj < H; ++jj)
                    hidd[jj] = fmaf(xv, ode_w1[kk * D + colBase + jj], hidd[jj]);
            }
#pragma unroll
            for (int jj = 0; jj < H; ++jj) hidd[jj] = fmaxf(hidd[jj], 0.0f);

            // publish hidd halves
            __syncthreads();
#pragma unroll
            for (int jj = 0; jj < H; ++jj) xbuf[colBase + jj][node_local] = hidd[jj];
            __syncthreads();

            // k = full_hidd @ W2 + b2, my 25 cols (into arg, dead now)
#pragma unroll
            for (int jj = 0; jj < H; ++jj) arg[jj] = ode_b2[colBase + jj];
#pragma unroll
            for (int kk = 0; kk < D; ++kk) {
                const float xv = xbuf[kk][node_local];
#pragma unroll
                for (int jj = 0; jj < H; ++jj)
                    arg[jj] = fmaf(xv, ode_w2[kk * D + colBase + jj], arg[jj]);
            }

            // acc += ca*k ; arg = y + cb*k
#pragma unroll
            for (int jj = 0; jj < H; ++jj) {
                const float kv = arg[jj];
                acc[jj] = fmaf(ca, kv, acc[jj]);
                arg[jj] = fmaf(cb, kv, y[jj]);
            }
        }
#pragma unroll
        for (int jj = 0; jj < H; ++jj) y[jj] = acc[jj];
        t += hh;
    }

    // ---------------- decoder ----------------
    // publish final y; colSel==0 threads run the (cheap) decoder + store.
    __syncthreads();
#pragma unroll
    for (int jj = 0; jj < H; ++jj) xbuf[colBase + jj][node_local] = y[jj];
    __syncthreads();

    if (colSel == 0) {
        float n2[16];
#pragma unroll
        for (int j = 0; j < 16; ++j) n2[j] = node_out_b[j];
#pragma unroll
        for (int kk = 0; kk < D; ++kk) {
            const float xv = xbuf[kk][node_local];
#pragma unroll
            for (int j = 0; j < 16; ++j)
                n2[j] = fmaf(xv, node_out_w[kk * 16 + j], n2[j]);
        }

        float dh[16];
#pragma unroll
        for (int j = 0; j < 16; ++j) dh[j] = dec_n_b1[j];
#pragma unroll
        for (int kk = 0; kk < 16; ++kk)
#pragma unroll
            for (int j = 0; j < 16; ++j)
                dh[j] = fmaf(n2[kk], dec_n_w1[kk * 16 + j], dh[j]);
#pragma unroll
        for (int j = 0; j < 16; ++j) dh[j] = swishf(dh[j]);

        float dh2[16];
#pragma unroll
        for (int j = 0; j < 16; ++j) dh2[j] = dec_n_b2[j];
#pragma unroll
        for (int kk = 0; kk < 16; ++kk)
#pragma unroll
            for (int j = 0; j < 16; ++j)
                dh2[j] = fmaf(dh[kk], dec_n_w2[kk * 16 + j], dh2[j]);
#pragma unroll
        for (int j = 0; j < 16; ++j) dh2[j] = swishf(dh2[j]);

        float pred = dec_n_b3[0];
#pragma unroll
        for (int kk = 0; kk < 16; ++kk) pred = fmaf(dh2[kk], dec_n_w3[kk], pred);

        if (active) {
            const float cur_pos = nodes[i * 5 + 0];
            const float n1 = nodes[i * 5 + 2];
            const float n2c = nodes[i * 5 + 3];
            const float cur_vel = nodes[i * 5 + 4];
            const float next_vel = fmaf(pred, DTC, cur_vel);
            const float next_pos = fmaf(next_vel, DTC, cur_pos);
            out[i * 6 + 0] = next_pos;
            out[i * 6 + 1] = n1;
            out[i * 6 + 2] = n2c;
            out[i * 6 + 3] = cur_vel;
            out[i * 6 + 4] = next_vel;
            out[i * 6 + 5] = pred;
        }
    }
}

// second pass: next_edges = diff(next_pos) read back from d_out, plus g_new
__global__ void gnode_edges(const float* __restrict__ out_nodes,
                            float* __restrict__ out,
                            const float* __restrict__ g)
{
    const int e = blockIdx.x * blockDim.x + threadIdx.x;
    if (e < EE) {
        out[NN * 6 + e] = out_nodes[(e + 1) * 6] - out_nodes[e * 6];
    }
    if (e == 0) {
        out[NN * 6 + EE]     = g[0] + 1.0f;
        out[NN * 6 + EE + 1] = g[1];
    }
}

extern "C" void kernel_launch(void* const* d_in, const int* in_sizes, int n_in,
                              void* d_out, int out_size, void* d_ws, size_t ws_size,
                              hipStream_t stream) {
    const float* nodes     = (const float*)d_in[0];
    const float* edges     = (const float*)d_in[1];
    const float* g         = (const float*)d_in[2];
    const float* enc_n_w1  = (const float*)d_in[3];
    const float* enc_n_b1  = (const float*)d_in[4];
    const float* enc_n_w2  = (const float*)d_in[5];
    const float* enc_n_b2  = (const float*)d_in[6];
    const float* enc_e_w1  = (const float*)d_in[7];
    const float* enc_e_b1  = (const float*)d_in[8];
    const float* enc_e_w2  = (const float*)d_in[9];
    const float* enc_e_b2  = (const float*)d_in[10];
    const float* ode_w1    = (const float*)d_in[11];
    const float* ode_b1    = (const float*)d_in[12];
    const float* ode_w2    = (const float*)d_in[13];
    const float* ode_b2    = (const float*)d_in[14];
    const float* node_out_w = (const float*)d_in[15];
    const float* node_out_b = (const float*)d_in[16];
    const float* dec_n_w1  = (const float*)d_in[17];
    const float* dec_n_b1  = (const float*)d_in[18];
    const float* dec_n_w2  = (const float*)d_in[19];
    const float* dec_n_b2  = (const float*)d_in[20];
    const float* dec_n_w3  = (const float*)d_in[21];
    const float* dec_n_b3  = (const float*)d_in[22];
    float* out = (float*)d_out;

    const int threads = 256;
    const int blocks = (NN + NPB - 1) / NPB;   // 1563 blocks of 128 nodes
    gnode_main<<<blocks, threads, 0, stream>>>(
        nodes, edges, g,
        enc_n_w1, enc_n_b1, enc_n_w2, enc_n_b2,
        enc_e_w1, enc_e_b1, enc_e_w2, enc_e_b2,
        ode_w1, ode_b1, ode_w2, ode_b2,
        node_out_w, node_out_b,
        dec_n_w1, dec_n_b1, dec_n_w2, dec_n_b2, dec_n_w3, dec_n_b3,
        out);

    gnode_edges<<<(EE + 255) / 256, 256, 0, stream>>>(out, out, g);
}

// Round 4
// 312.282 us; speedup vs baseline: 8.6994x; 6.5061x over previous
//
#include <hip/hip_runtime.h>

#define NN 200000
#define EE (NN - 1)
#define DLAT 50
#define K1ROWS 51
#define NSTEPS 4
#define DTC 0.01f
#define RS 136            // scratch row stride in ushorts (272 B) — pad keeps b128 reads 2-way max
#define NPW 16            // nodes per wave (one 16-row MFMA tile)
#define WPB 4             // waves per block
#define NPB (NPW * WPB)   // 64 nodes per block; 200000 = 64 * 3125 exactly (no tail)

typedef __attribute__((ext_vector_type(8))) short short8;
typedef __attribute__((ext_vector_type(4))) float f32x4;

__device__ __forceinline__ unsigned short f2bf(float f) {
    unsigned u = __float_as_uint(f);
    u += 0x7FFF + ((u >> 16) & 1);          // RNE
    return (unsigned short)(u >> 16);
}
__device__ __forceinline__ float bf2f(unsigned short s) {
    return __uint_as_float(((unsigned)s) << 16);
}
__device__ __forceinline__ float swishf(float x) { return x / (1.0f + __expf(-x)); }

__device__ __forceinline__ void edge_enc(float ev,
                                         const float* __restrict__ w1,
                                         const float* __restrict__ b1,
                                         const float* __restrict__ w2,
                                         const float* __restrict__ b2,
                                         float* outv) {
    float h[16];
#pragma unroll
    for (int j = 0; j < 16; ++j) h[j] = swishf(fmaf(ev, w1[j], b1[j]));
#pragma unroll
    for (int j = 0; j < 16; ++j) {
        float s = b2[j];
#pragma unroll
        for (int k = 0; k < 16; ++k) s = fmaf(h[k], w2[k * 16 + j], s);
        outv[j] = s;
    }
}

// One wave = 16 nodes. ODE RK4 stages run as bf16 MFMA GEMMs with weights
// held in registers as B-fragments; C->A relayout via per-wave private LDS
// (no __syncthreads anywhere). y/acc kept fp32 in MFMA C-layout registers.
__global__ __launch_bounds__(256)
void gnode_main(const float* __restrict__ nodes,
                const float* __restrict__ edges,
                const float* __restrict__ g,
                const float* __restrict__ enc_n_w1, const float* __restrict__ enc_n_b1,
                const float* __restrict__ enc_n_w2, const float* __restrict__ enc_n_b2,
                const float* __restrict__ enc_e_w1, const float* __restrict__ enc_e_b1,
                const float* __restrict__ enc_e_w2, const float* __restrict__ enc_e_b2,
                const float* __restrict__ ode_w1, const float* __restrict__ ode_b1,
                const float* __restrict__ ode_w2, const float* __restrict__ ode_b2,
                const float* __restrict__ node_out_w, const float* __restrict__ node_out_b,
                const float* __restrict__ dec_n_w1, const float* __restrict__ dec_n_b1,
                const float* __restrict__ dec_n_w2, const float* __restrict__ dec_n_b2,
                const float* __restrict__ dec_n_w3, const float* __restrict__ dec_n_b3,
                float* __restrict__ out)
{
    __shared__ __attribute__((aligned(16))) unsigned short sc[WPB][NPW][RS];

    const int tid  = threadIdx.x;
    const int lane = tid & 63;
    const int wave = __builtin_amdgcn_readfirstlane(tid >> 6);
    const int m = lane & 15;      // A-row / node index in tile; also C-col index
    const int q = lane >> 4;      // quad
    unsigned short* wb = &sc[wave][0][0];
    const int node = blockIdx.x * NPB + wave * NPW + m;   // always < NN (exact grid)

    // ---- build W1/W2 B-fragments in registers (bf16), zero-padded to 64x64 ----
    // B layout (16x16x32): lane holds B[k = q*8+j + 32*kt][n = nt*16 + m]
    short8 w1f[2][4], w2f[2][4];
#pragma unroll
    for (int kt = 0; kt < 2; ++kt) {
#pragma unroll
        for (int nt = 0; nt < 4; ++nt) {
            short8 f1, f2;
#pragma unroll
            for (int j = 0; j < 8; ++j) {
                const int k = kt * 32 + q * 8 + j;
                const int n = nt * 16 + m;
                const float v1 = (k < K1ROWS && n < DLAT) ? ode_w1[k * DLAT + n] : 0.0f;
                const float v2 = (k < DLAT  && n < DLAT) ? ode_w2[k * DLAT + n] : 0.0f;
                f1[j] = (short)f2bf(v1);
                f2[j] = (short)f2bf(v2);
            }
            w1f[kt][nt] = f1;
            w2f[kt][nt] = f2;
        }
    }
    float b1v[4], b2v[4];
#pragma unroll
    for (int ct = 0; ct < 4; ++ct) {
        const int col = ct * 16 + m;
        b1v[ct] = (col < DLAT) ? ode_b1[col] : 0.0f;
        b2v[ct] = (col < DLAT) ? ode_b2[col] : 0.0f;
    }

    // ---- encoder: quad q fills cols q*16..q*16+15 of node m's y0 row ----
    {
        unsigned short vals[16];
        if (q == 0) {                 // nlat (cols 0..15)
            float nf[5];
#pragma unroll
            for (int c = 0; c < 5; ++c) nf[c] = nodes[node * 5 + c];
            float h16[16];
#pragma unroll
            for (int j = 0; j < 16; ++j) h16[j] = enc_n_b1[j];
#pragma unroll
            for (int c = 0; c < 5; ++c)
#pragma unroll
                for (int j = 0; j < 16; ++j)
                    h16[j] = fmaf(nf[c], enc_n_w1[c * 16 + j], h16[j]);
#pragma unroll
            for (int j = 0; j < 16; ++j) h16[j] = swishf(h16[j]);
#pragma unroll
            for (int j = 0; j < 16; ++j) {
                float s = enc_n_b2[j];
#pragma unroll
                for (int k = 0; k < 16; ++k) s = fmaf(h16[k], enc_n_w2[k * 16 + j], s);
                vals[j] = f2bf(s);
            }
        } else if (q == 1) {          // sent = elat[node] (cols 16..31)
            float els[16];
            if (node < EE) {
                edge_enc(edges[node], enc_e_w1, enc_e_b1, enc_e_w2, enc_e_b2, els);
            } else {
#pragma unroll
                for (int j = 0; j < 16; ++j) els[j] = 0.0f;
            }
#pragma unroll
            for (int j = 0; j < 16; ++j) vals[j] = f2bf(els[j]);
        } else if (q == 2) {          // recv = elat[node-1] (cols 32..47)
            float elr[16];
            if (node > 0) {
                edge_enc(edges[node - 1], enc_e_w1, enc_e_b1, enc_e_w2, enc_e_b2, elr);
            } else {
#pragma unroll
                for (int j = 0; j < 16; ++j) elr[j] = 0.0f;
            }
#pragma unroll
            for (int j = 0; j < 16; ++j) vals[j] = f2bf(elr[j]);
        } else {                      // g, t=0, zero pad (cols 48..63)
            vals[0] = f2bf(g[0]);
            vals[1] = f2bf(g[1]);
#pragma unroll
            for (int j = 2; j < 16; ++j) vals[j] = 0;    // col 50 = t0 = 0
        }
        short8 p0, p1;
#pragma unroll
        for (int j = 0; j < 8; ++j) { p0[j] = (short)vals[j]; p1[j] = (short)vals[8 + j]; }
        *(short8*)(wb + m * RS + q * 16)     = p0;
        *(short8*)(wb + m * RS + q * 16 + 8) = p1;
    }

    // ---- pull y0 into fp32 C-layout regs: lane holds col=ct*16+m(lane&15), row=q*4+r ----
    float y_c[4][4], acc_c[4][4];
#pragma unroll
    for (int ct = 0; ct < 4; ++ct)
#pragma unroll
        for (int r = 0; r < 4; ++r)
            y_c[ct][r] = bf2f(wb[(q * 4 + r) * RS + ct * 16 + m]);

    // ---- RK4: 16 stages, each = GEMM1(relu) -> GEMM2 -> combine -> relayout ----
    const float hh = 1.0f / NSTEPS;
    float t0 = 0.0f;

#pragma clang loop unroll(disable)
    for (int stage = 0; stage < 4 * NSTEPS; ++stage) {
        const int s = stage & 3;

        // A-frags of arg (bf16): lane reads row m, k = 32*kt + q*8 + 0..7
        short8 a0 = *(const short8*)(wb + m * RS + q * 8);
        short8 a1 = *(const short8*)(wb + m * RS + 32 + q * 8);

        // GEMM1: hid = relu(arg @ W1 + t*W1[50] + b1)  (t rides in A at k=50)
        f32x4 hc[4];
#pragma unroll
        for (int ct = 0; ct < 4; ++ct) {
            f32x4 c;
            c[0] = b1v[ct]; c[1] = b1v[ct]; c[2] = b1v[ct]; c[3] = b1v[ct];
            c = __builtin_amdgcn_mfma_f32_16x16x32_bf16(a0, w1f[0][ct], c, 0, 0, 0);
            c = __builtin_amdgcn_mfma_f32_16x16x32_bf16(a1, w1f[1][ct], c, 0, 0, 0);
            hc[ct] = c;
        }
        // relu + C->A relayout through private LDS (cols>=50 are exactly 0)
#pragma unroll
        for (int ct = 0; ct < 4; ++ct)
#pragma unroll
            for (int r = 0; r < 4; ++r)
                wb[(q * 4 + r) * RS + ct * 16 + m] = f2bf(fmaxf(hc[ct][r], 0.0f));

        short8 h0 = *(const short8*)(wb + m * RS + q * 8);
        short8 h1 = *(const short8*)(wb + m * RS + 32 + q * 8);

        // GEMM2: k = hid @ W2 + b2
        f32x4 kc[4];
#pragma unroll
        for (int ct = 0; ct < 4; ++ct) {
            f32x4 c;
            c[0] = b2v[ct]; c[1] = b2v[ct]; c[2] = b2v[ct]; c[3] = b2v[ct];
            c = __builtin_amdgcn_mfma_f32_16x16x32_bf16(h0, w2f[0][ct], c, 0, 0, 0);
            c = __builtin_amdgcn_mfma_f32_16x16x32_bf16(h1, w2f[1][ct], c, 0, 0, 0);
            kc[ct] = c;
        }

        // RK4 combine (fp32, C-layout)
        const float ca = (s == 0 || s == 3) ? hh / 6.0f : hh / 3.0f;
#pragma unroll
        for (int ct = 0; ct < 4; ++ct)
#pragma unroll
            for (int r = 0; r < 4; ++r) {
                const float base = (s == 0) ? y_c[ct][r] : acc_c[ct][r];
                acc_c[ct][r] = fmaf(ca, kc[ct][r], base);
            }

        float argv[4][4];
        float tn;
        if (s < 3) {
            const float cb = (s == 2) ? hh : 0.5f * hh;
#pragma unroll
            for (int ct = 0; ct < 4; ++ct)
#pragma unroll
                for (int r = 0; r < 4; ++r)
                    argv[ct][r] = fmaf(cb, kc[ct][r], y_c[ct][r]);
            tn = t0 + cb;
        } else {
#pragma unroll
            for (int ct = 0; ct < 4; ++ct)
#pragma unroll
                for (int r = 0; r < 4; ++r) {
                    y_c[ct][r] = acc_c[ct][r];       // y_{step+1}
                    argv[ct][r] = acc_c[ct][r];
                }
            t0 += hh;
            tn = t0;
        }

        // relayout arg for next stage; slot col=50 carries t (bf16-exact: k/8)
#pragma unroll
        for (int ct = 0; ct < 4; ++ct)
#pragma unroll
            for (int r = 0; r < 4; ++r) {
                float v = argv[ct][r];
                if (ct == 3) v = (m == 2) ? tn : v;   // col 48+m==50
                wb[(q * 4 + r) * RS + ct * 16 + m] = f2bf(v);
            }
    }

    // ---- publish final y (bf16) for the decoder ----
#pragma unroll
    for (int ct = 0; ct < 4; ++ct)
#pragma unroll
        for (int r = 0; r < 4; ++r)
            wb[(q * 4 + r) * RS + ct * 16 + m] = f2bf(y_c[ct][r]);

    // ---- decoder: lanes 0..15 (q==0), one node each ----
    if (q == 0) {
        float n2[16];
#pragma unroll
        for (int j = 0; j < 16; ++j) n2[j] = node_out_b[j];
        for (int k = 0; k < DLAT; ++k) {
            const float xv = bf2f(wb[m * RS + k]);
#pragma unroll
            for (int j = 0; j < 16; ++j)
                n2[j] = fmaf(xv, node_out_w[k * 16 + j], n2[j]);
        }
        float dh[16];
#pragma unroll
        for (int j = 0; j < 16; ++j) dh[j] = dec_n_b1[j];
#pragma unroll
        for (int k = 0; k < 16; ++k)
#pragma unroll
            for (int j = 0; j < 16; ++j)
                dh[j] = fmaf(n2[k], dec_n_w1[k * 16 + j], dh[j]);
#pragma unroll
        for (int j = 0; j < 16; ++j) dh[j] = swishf(dh[j]);

        float dh2[16];
#pragma unroll
        for (int j = 0; j < 16; ++j) dh2[j] = dec_n_b2[j];
#pragma unroll
        for (int k = 0; k < 16; ++k)
#pragma unroll
            for (int j = 0; j < 16; ++j)
                dh2[j] = fmaf(dh[k], dec_n_w2[k * 16 + j], dh2[j]);
#pragma unroll
        for (int j = 0; j < 16; ++j) dh2[j] = swishf(dh2[j]);

        float pred = dec_n_b3[0];
#pragma unroll
        for (int k = 0; k < 16; ++k) pred = fmaf(dh2[k], dec_n_w3[k], pred);

        const float cur_pos = nodes[node * 5 + 0];
        const float c2 = nodes[node * 5 + 2];
        const float c3 = nodes[node * 5 + 3];
        const float cur_vel = nodes[node * 5 + 4];
        const float next_vel = fmaf(pred, DTC, cur_vel);
        const float next_pos = fmaf(next_vel, DTC, cur_pos);
        out[node * 6 + 0] = next_pos;
        out[node * 6 + 1] = c2;
        out[node * 6 + 2] = c3;
        out[node * 6 + 3] = cur_vel;
        out[node * 6 + 4] = next_vel;
        out[node * 6 + 5] = pred;
    }
}

// second pass: next_edges = diff(next_pos) read back from d_out, plus g_new
__global__ void gnode_edges(const float* __restrict__ out_nodes,
                            float* __restrict__ out,
                            const float* __restrict__ g)
{
    const int e = blockIdx.x * blockDim.x + threadIdx.x;
    if (e < EE) {
        out[NN * 6 + e] = out_nodes[(e + 1) * 6] - out_nodes[e * 6];
    }
    if (e == 0) {
        out[NN * 6 + EE]     = g[0] + 1.0f;
        out[NN * 6 + EE + 1] = g[1];
    }
}

extern "C" void kernel_launch(void* const* d_in, const int* in_sizes, int n_in,
                              void* d_out, int out_size, void* d_ws, size_t ws_size,
                              hipStream_t stream) {
    const float* nodes      = (const float*)d_in[0];
    const float* edges      = (const float*)d_in[1];
    const float* g          = (const float*)d_in[2];
    const float* enc_n_w1   = (const float*)d_in[3];
    const float* enc_n_b1   = (const float*)d_in[4];
    const float* enc_n_w2   = (const float*)d_in[5];
    const float* enc_n_b2   = (const float*)d_in[6];
    const float* enc_e_w1   = (const float*)d_in[7];
    const float* enc_e_b1   = (const float*)d_in[8];
    const float* enc_e_w2   = (const float*)d_in[9];
    const float* enc_e_b2   = (const float*)d_in[10];
    const float* ode_w1     = (const float*)d_in[11];
    const float* ode_b1     = (const float*)d_in[12];
    const float* ode_w2     = (const float*)d_in[13];
    const float* ode_b2     = (const float*)d_in[14];
    const float* node_out_w = (const float*)d_in[15];
    const float* node_out_b = (const float*)d_in[16];
    const float* dec_n_w1   = (const float*)d_in[17];
    const float* dec_n_b1   = (const float*)d_in[18];
    const float* dec_n_w2   = (const float*)d_in[19];
    const float* dec_n_b2   = (const float*)d_in[20];
    const float* dec_n_w3   = (const float*)d_in[21];
    const float* dec_n_b3   = (const float*)d_in[22];
    float* out = (float*)d_out;

    const int blocks = NN / NPB;   // 3125, exact
    gnode_main<<<blocks, 256, 0, stream>>>(
        nodes, edges, g,
        enc_n_w1, enc_n_b1, enc_n_w2, enc_n_b2,
        enc_e_w1, enc_e_b1, enc_e_w2, enc_e_b2,
        ode_w1, ode_b1, ode_w2, ode_b2,
        node_out_w, node_out_b,
        dec_n_w1, dec_n_b1, dec_n_w2, dec_n_b2, dec_n_w3, dec_n_b3,
        out);

    gnode_edges<<<(EE + 255) / 256, 256, 0, stream>>>(out, out, g);
}

// Round 5
// 249.416 us; speedup vs baseline: 10.8921x; 1.2521x over previous
//
#include <hip/hip_runtime.h>
#include <hip/hip_bf16.h>

#define NN 200000
#define EE (NN - 1)
#define NSTEPS 4
#define DTC 0.01f
#define RS 72             // ushorts per LDS row (144 B): 16B-aligned rows, bank-staggered
#define WPB 4
#define NPB 64            // 64 nodes/block; 200000 = 64 * 3125 exactly

typedef __attribute__((ext_vector_type(8))) short short8;
typedef __attribute__((ext_vector_type(4))) float f32x4;

__device__ __forceinline__ unsigned short f2bf(float f) {
    unsigned u = __float_as_uint(f);
    u += 0x7FFF + ((u >> 16) & 1);          // RNE
    return (unsigned short)(u >> 16);
}
__device__ __forceinline__ unsigned pk2(float lo, float hi) {
    union { __hip_bfloat162 h2; unsigned u; } cv;
    cv.h2 = __float22bfloat162_rn(make_float2(lo, hi));   // v_cvt_pk_bf16_f32 on gfx950
    return cv.u;
}
__device__ __forceinline__ float swishf(float x) { return x / (1.0f + __expf(-x)); }

// Flipped-orientation MFMA pipeline: D = W^T (A) · act^T (B).
// C-layout: lane(q,m) holds D[dim = ct*16 + q*4 + r][node = m] -> each lane's
// 4 values are CONTIGUOUS dims of node m's LDS row => packed b64 relayout.
// Biases ride in the GEMM K-dim (arg col 51 = 1.0 pairs with W1ext row 51 = b1;
// hid col 50 = 1.0 pairs with W2ext row 50 = b2). All LDS is per-wave private.
__global__ __launch_bounds__(256)
void gnode_main(const float* __restrict__ nodes,
                const float* __restrict__ edges,
                const float* __restrict__ g,
                const float* __restrict__ enc_n_w1, const float* __restrict__ enc_n_b1,
                const float* __restrict__ enc_n_w2, const float* __restrict__ enc_n_b2,
                const float* __restrict__ enc_e_w1, const float* __restrict__ enc_e_b1,
                const float* __restrict__ enc_e_w2, const float* __restrict__ enc_e_b2,
                const float* __restrict__ ode_w1, const float* __restrict__ ode_b1,
                const float* __restrict__ ode_w2, const float* __restrict__ ode_b2,
                const float* __restrict__ node_out_w, const float* __restrict__ node_out_b,
                const float* __restrict__ dec_n_w1, const float* __restrict__ dec_n_b1,
                const float* __restrict__ dec_n_w2, const float* __restrict__ dec_n_b2,
                const float* __restrict__ dec_n_w3, const float* __restrict__ dec_n_b3,
                float* __restrict__ out)
{
    __shared__ __attribute__((aligned(16))) unsigned short sc[WPB][16][RS];

    const int tid  = threadIdx.x;
    const int lane = tid & 63;
    const int wave = __builtin_amdgcn_readfirstlane(tid >> 6);
    const int m = lane & 15;          // node-in-tile (A-row / C-col)
    const int q = lane >> 4;          // quad
    unsigned short* wb = &sc[wave][0][0];
    unsigned short* wrow = wb + m * RS + q * 4;   // packed-write base (dims q*4.. per ct)
    const unsigned short* rrow = wb + m * RS + q * 8; // b128-read base (k = q*8+j per kt)
    const int node = blockIdx.x * NPB + wave * 16 + m;   // exact grid, no tail

    const f32x4 zero4 = {0.f, 0.f, 0.f, 0.f};
    f32x4 y[4];      // y0 in C-layout: y[ct][r] = state[node=m][dim=ct*16+q*4+r]

    // ================= encoder (3 MFMAs, bias via C-operand) =================
    // zero dims 16..31 of row m once (K=32 enc GEMMs read zeros there)
    *(uint2*)(wrow + 16) = make_uint2(0u, 0u);

    // enc weight frags: A[m][k=q*8+j] = W2[k][m] (K=16 real, pad 0)
    short8 wN, wE;
#pragma unroll
    for (int j = 0; j < 8; ++j) {
        const int k = q * 8 + j;
        wN[j] = (short)((k < 16) ? f2bf(enc_n_w2[k * 16 + m]) : 0);
        wE[j] = (short)((k < 16) ? f2bf(enc_e_w2[k * 16 + m]) : 0);
    }
    f32x4 bN, bE;
#pragma unroll
    for (int r = 0; r < 4; ++r) { bN[r] = enc_n_b2[q * 4 + r]; bE[r] = enc_e_b2[q * 4 + r]; }

    // --- node-enc hidden: lane computes h[node=m][dims q*4..q*4+3] ---
    {
        float nf[5];
#pragma unroll
        for (int c = 0; c < 5; ++c) nf[c] = nodes[node * 5 + c];
        float hv[4];
#pragma unroll
        for (int r = 0; r < 4; ++r) {
            const int d = q * 4 + r;
            float s = enc_n_b1[d];
#pragma unroll
            for (int c = 0; c < 5; ++c) s = fmaf(nf[c], enc_n_w1[c * 16 + d], s);
            hv[r] = swishf(s);
        }
        *(uint2*)(wrow) = make_uint2(pk2(hv[0], hv[1]), pk2(hv[2], hv[3]));
        short8 fr = *(const short8*)(rrow);
        y[0] = __builtin_amdgcn_mfma_f32_16x16x32_bf16(wN, fr, bN, 0, 0, 0);   // nlat
    }
    // --- sent = elat[node] ---
    {
        const float ev = (node < EE) ? edges[node] : 0.0f;
        float hv[4];
#pragma unroll
        for (int r = 0; r < 4; ++r) {
            const int d = q * 4 + r;
            hv[r] = swishf(fmaf(ev, enc_e_w1[d], enc_e_b1[d]));
        }
        *(uint2*)(wrow) = make_uint2(pk2(hv[0], hv[1]), pk2(hv[2], hv[3]));
        short8 fr = *(const short8*)(rrow);
        y[1] = __builtin_amdgcn_mfma_f32_16x16x32_bf16(wE, fr, bE, 0, 0, 0);
        if (node == NN - 1) y[1] = zero4;           // no outgoing edge
    }
    // --- recv = elat[node-1] ---
    {
        const float ev = (node > 0) ? edges[node - 1] : 0.0f;
        float hv[4];
#pragma unroll
        for (int r = 0; r < 4; ++r) {
            const int d = q * 4 + r;
            hv[r] = swishf(fmaf(ev, enc_e_w1[d], enc_e_b1[d]));
        }
        *(uint2*)(wrow) = make_uint2(pk2(hv[0], hv[1]), pk2(hv[2], hv[3]));
        short8 fr = *(const short8*)(rrow);
        y[2] = __builtin_amdgcn_mfma_f32_16x16x32_bf16(wE, fr, bE, 0, 0, 0);
        if (node == 0) y[2] = zero4;                // no incoming edge
    }
    // --- dims 48..63: g at 48,49 (they DO evolve); rest 0 ---
    y[3] = zero4;
    if (q == 0) { y[3][0] = g[0]; y[3][1] = g[1]; }

    // ============== ODE weight A-frags (built once, 64 VGPRs) ==============
    // W1ext rows: 0..49 = W1 state, 50 = W1[50] (t), 51 = b1, 52..63 = 0
    // W2ext rows: 0..49 = W2, 50 = b2, 51..63 = 0
    short8 w1f[2][4], w2f[2][4];
#pragma unroll
    for (int kt = 0; kt < 2; ++kt) {
#pragma unroll
        for (int ct = 0; ct < 4; ++ct) {
            short8 f1, f2;
#pragma unroll
            for (int j = 0; j < 8; ++j) {
                const int k = kt * 32 + q * 8 + j;
                const int od = ct * 16 + m;
                float v1 = 0.0f, v2 = 0.0f;
                if (od < 50) {
                    if (k < 51) v1 = ode_w1[k * 50 + od];
                    else if (k == 51) v1 = ode_b1[od];
                    if (k < 50) v2 = ode_w2[k * 50 + od];
                    else if (k == 50) v2 = ode_b2[od];
                }
                f1[j] = (short)f2bf(v1);
                f2[j] = (short)f2bf(v2);
            }
            w1f[kt][ct] = f1;
            w2f[kt][ct] = f2;
        }
    }

    // ============================ RK4 (16 stages) ============================
    const float hh = 1.0f / NSTEPS;
    float t0 = 0.0f;
    f32x4 acc[4];

    // initial arg0 = y0 (t slot = 0, one slot = 1)
#pragma unroll
    for (int ct = 0; ct < 4; ++ct) {
        float x0 = y[ct][0], x1 = y[ct][1], x2 = y[ct][2], x3 = y[ct][3];
        if (ct == 3 && q == 0) { x2 = 0.0f; x3 = 1.0f; }
        *(uint2*)(wrow + ct * 16) = make_uint2(pk2(x0, x1), pk2(x2, x3));
    }

#pragma clang loop unroll(disable)
    for (int stage = 0; stage < 4 * NSTEPS; ++stage) {
        const int s = stage & 3;

        short8 bA = *(const short8*)(rrow);
        short8 bB = *(const short8*)(rrow + 32);
        f32x4 hc[4];
#pragma unroll
        for (int ct = 0; ct < 4; ++ct) {
            f32x4 c = __builtin_amdgcn_mfma_f32_16x16x32_bf16(w1f[0][ct], bA, zero4, 0, 0, 0);
            hc[ct]  = __builtin_amdgcn_mfma_f32_16x16x32_bf16(w1f[1][ct], bB, c, 0, 0, 0);
        }
        // relu + packed relayout (hid col 50 <- 1.0 for bias fold)
#pragma unroll
        for (int ct = 0; ct < 4; ++ct) {
            float x0 = fmaxf(hc[ct][0], 0.f), x1 = fmaxf(hc[ct][1], 0.f);
            float x2 = fmaxf(hc[ct][2], 0.f), x3 = fmaxf(hc[ct][3], 0.f);
            if (ct == 3 && q == 0) x2 = 1.0f;
            *(uint2*)(wrow + ct * 16) = make_uint2(pk2(x0, x1), pk2(x2, x3));
        }
        short8 hA = *(const short8*)(rrow);
        short8 hB = *(const short8*)(rrow + 32);
        f32x4 kc[4];
#pragma unroll
        for (int ct = 0; ct < 4; ++ct) {
            f32x4 c = __builtin_amdgcn_mfma_f32_16x16x32_bf16(w2f[0][ct], hA, zero4, 0, 0, 0);
            kc[ct]  = __builtin_amdgcn_mfma_f32_16x16x32_bf16(w2f[1][ct], hB, c, 0, 0, 0);
        }

        const float ca = (s == 0 || s == 3) ? hh / 6.0f : hh / 3.0f;
        if (s == 0) {
#pragma unroll
            for (int ct = 0; ct < 4; ++ct) acc[ct] = y[ct] + ca * kc[ct];
        } else {
#pragma unroll
            for (int ct = 0; ct < 4; ++ct) acc[ct] = acc[ct] + ca * kc[ct];
        }

        f32x4 av[4];
        float tn;
        if (s < 3) {
            const float cb = (s == 2) ? hh : 0.5f * hh;
#pragma unroll
            for (int ct = 0; ct < 4; ++ct) av[ct] = y[ct] + cb * kc[ct];
            tn = t0 + cb;
        } else {
#pragma unroll
            for (int ct = 0; ct < 4; ++ct) { y[ct] = acc[ct]; av[ct] = acc[ct]; }
            t0 += hh;
            tn = t0;
        }
        // write next arg (last stage doubles as y-publish; dims 50/51 content
        // is masked in the decoder GEMM by zero A-rows)
#pragma unroll
        for (int ct = 0; ct < 4; ++ct) {
            float x0 = av[ct][0], x1 = av[ct][1], x2 = av[ct][2], x3 = av[ct][3];
            if (ct == 3 && q == 0) { x2 = tn; x3 = 1.0f; }
            *(uint2*)(wrow + ct * 16) = make_uint2(pk2(x0, x1), pk2(x2, x3));
        }
    }

    // ========================== decoder (4 MFMAs) ==========================
    short8 ow0, ow1, dw1, dw2;
#pragma unroll
    for (int j = 0; j < 8; ++j) {
        const int k0 = q * 8 + j, k1 = 32 + q * 8 + j;
        ow0[j] = (short)((k0 < 50) ? f2bf(node_out_w[k0 * 16 + m]) : 0);
        ow1[j] = (short)((k1 < 50) ? f2bf(node_out_w[k1 * 16 + m]) : 0);
        dw1[j] = (short)((k0 < 16) ? f2bf(dec_n_w1[k0 * 16 + m]) : 0);
        dw2[j] = (short)((k0 < 16) ? f2bf(dec_n_w2[k0 * 16 + m]) : 0);
    }
    f32x4 bO, bD1, bD2;
    float w3v[4];
#pragma unroll
    for (int r = 0; r < 4; ++r) {
        bO[r]  = node_out_b[q * 4 + r];
        bD1[r] = dec_n_b1[q * 4 + r];
        bD2[r] = dec_n_b2[q * 4 + r];
        w3v[r] = dec_n_w3[q * 4 + r];
    }

    short8 yA = *(const short8*)(rrow);
    short8 yB = *(const short8*)(rrow + 32);
    f32x4 nl2 = __builtin_amdgcn_mfma_f32_16x16x32_bf16(ow0, yA, bO, 0, 0, 0);
    nl2       = __builtin_amdgcn_mfma_f32_16x16x32_bf16(ow1, yB, nl2, 0, 0, 0);

    // relayout nl2 (dims 0..15) + zero 16..31 for the K=32 dec GEMMs
    *(uint2*)(wrow)      = make_uint2(pk2(nl2[0], nl2[1]), pk2(nl2[2], nl2[3]));
    *(uint2*)(wrow + 16) = make_uint2(0u, 0u);
    short8 nA = *(const short8*)(rrow);
    f32x4 dh = __builtin_amdgcn_mfma_f32_16x16x32_bf16(dw1, nA, bD1, 0, 0, 0);
#pragma unroll
    for (int r = 0; r < 4; ++r) dh[r] = swishf(dh[r]);

    *(uint2*)(wrow) = make_uint2(pk2(dh[0], dh[1]), pk2(dh[2], dh[3]));
    short8 dA = *(const short8*)(rrow);
    f32x4 dh2 = __builtin_amdgcn_mfma_f32_16x16x32_bf16(dw2, dA, bD2, 0, 0, 0);
#pragma unroll
    for (int r = 0; r < 4; ++r) dh2[r] = swishf(dh2[r]);

    // pred[m] = sum_d dh2[m][d]*w3[d] : per-lane partial + cross-quad reduce
    float p = dh2[0] * w3v[0];
    p = fmaf(dh2[1], w3v[1], p);
    p = fmaf(dh2[2], w3v[2], p);
    p = fmaf(dh2[3], w3v[3], p);
    p += __shfl_xor(p, 16);
    p += __shfl_xor(p, 32);
    p += dec_n_b3[0];

    if (q == 0) {
        const float cur_pos = nodes[node * 5 + 0];
        const float c2 = nodes[node * 5 + 2];
        const float c3 = nodes[node * 5 + 3];
        const float cur_vel = nodes[node * 5 + 4];
        const float next_vel = fmaf(p, DTC, cur_vel);
        const float next_pos = fmaf(next_vel, DTC, cur_pos);
        out[node * 6 + 0] = next_pos;
        out[node * 6 + 1] = c2;
        out[node * 6 + 2] = c3;
        out[node * 6 + 3] = cur_vel;
        out[node * 6 + 4] = next_vel;
        out[node * 6 + 5] = p;
    }
}

// second pass: next_edges = diff(next_pos) read back from d_out, plus g_new
__global__ void gnode_edges(const float* __restrict__ out_nodes,
                            float* __restrict__ out,
                            const float* __restrict__ g)
{
    const int e = blockIdx.x * blockDim.x + threadIdx.x;
    if (e < EE) {
        out[NN * 6 + e] = out_nodes[(e + 1) * 6] - out_nodes[e * 6];
    }
    if (e == 0) {
        out[NN * 6 + EE]     = g[0] + 1.0f;
        out[NN * 6 + EE + 1] = g[1];
    }
}

extern "C" void kernel_launch(void* const* d_in, const int* in_sizes, int n_in,
                              void* d_out, int out_size, void* d_ws, size_t ws_size,
                              hipStream_t stream) {
    const float* nodes      = (const float*)d_in[0];
    const float* edges      = (const float*)d_in[1];
    const float* g          = (const float*)d_in[2];
    const float* enc_n_w1   = (const float*)d_in[3];
    const float* enc_n_b1   = (const float*)d_in[4];
    const float* enc_n_w2   = (const float*)d_in[5];
    const float* enc_n_b2   = (const float*)d_in[6];
    const float* enc_e_w1   = (const float*)d_in[7];
    const float* enc_e_b1   = (const float*)d_in[8];
    const float* enc_e_w2   = (const float*)d_in[9];
    const float* enc_e_b2   = (const float*)d_in[10];
    const float* ode_w1     = (const float*)d_in[11];
    const float* ode_b1     = (const float*)d_in[12];
    const float* ode_w2     = (const float*)d_in[13];
    const float* ode_b2     = (const float*)d_in[14];
    const float* node_out_w = (const float*)d_in[15];
    const float* node_out_b = (const float*)d_in[16];
    const float* dec_n_w1   = (const float*)d_in[17];
    const float* dec_n_b1   = (const float*)d_in[18];
    const float* dec_n_w2   = (const float*)d_in[19];
    const float* dec_n_b2   = (const float*)d_in[20];
    const float* dec_n_w3   = (const float*)d_in[21];
    const float* dec_n_b3   = (const float*)d_in[22];
    float* out = (float*)d_out;

    const int blocks = NN / NPB;   // 3125, exact
    gnode_main<<<blocks, 256, 0, stream>>>(
        nodes, edges, g,
        enc_n_w1, enc_n_b1, enc_n_w2, enc_n_b2,
        enc_e_w1, enc_e_b1, enc_e_w2, enc_e_b2,
        ode_w1, ode_b1, ode_w2, ode_b2,
        node_out_w, node_out_b,
        dec_n_w1, dec_n_b1, dec_n_w2, dec_n_b2, dec_n_w3, dec_n_b3,
        out);

    gnode_edges<<<(EE + 255) / 256, 256, 0, stream>>>(out, out, g);
}

// Round 6
// 215.084 us; speedup vs baseline: 12.6308x; 1.1596x over previous
//
#include <hip/hip_runtime.h>
#include <hip/hip_bf16.h>

#define NN 200000
#define EE (NN - 1)
#define NSTEPS 4
#define DTC 0.01f
#define WPB 4
#define NPB 64            // 64 nodes/block; 200000 = 64 * 3125 exactly

typedef __attribute__((ext_vector_type(8))) short short8;
typedef __attribute__((ext_vector_type(4))) float f32x4;

__device__ __forceinline__ unsigned pk2(float lo, float hi) {
    union { __hip_bfloat162 h2; unsigned u; } cv;
    cv.h2 = __float22bfloat162_rn(make_float2(lo, hi));   // v_cvt_pk_bf16_f32
    return cv.u;
}
__device__ __forceinline__ float swishf(float x) { return x / (1.0f + __expf(-x)); }

// Flipped-orientation MFMA pipeline (D = W^T · act^T), with:
//  - block-cooperative bf16 weight staging in LDS (frag build amortized over
//    4 waves x 64 lanes instead of per-lane scattered loads)   [R5: ~2.5k VALU/wave]
//  - XOR-swizzled per-wave scratch (chunk ^= m&7, row stride 64 ushorts):
//    uniform bank spread (reads 8/bank, writes 4/bank = minimum), pointers
//    hoisted out of the stage loop                              [R5: 10.5M conflict cyc]
// Biases ride in the GEMM K-dim (arg col 51 = 1.0 -> b1; hid col 50 = 1.0 -> b2).
__global__ __launch_bounds__(256)
void gnode_main(const float* __restrict__ nodes,
                const float* __restrict__ edges,
                const float* __restrict__ g,
                const float* __restrict__ enc_n_w1, const float* __restrict__ enc_n_b1,
                const float* __restrict__ enc_n_w2, const float* __restrict__ enc_n_b2,
                const float* __restrict__ enc_e_w1, const float* __restrict__ enc_e_b1,
                const float* __restrict__ enc_e_w2, const float* __restrict__ enc_e_b2,
                const float* __restrict__ ode_w1, const float* __restrict__ ode_b1,
                const float* __restrict__ ode_w2, const float* __restrict__ ode_b2,
                const float* __restrict__ node_out_w, const float* __restrict__ node_out_b,
                const float* __restrict__ dec_n_w1, const float* __restrict__ dec_n_b1,
                const float* __restrict__ dec_n_w2, const float* __restrict__ dec_n_b2,
                const float* __restrict__ dec_n_w3, const float* __restrict__ dec_n_b3,
                float* __restrict__ out)
{
    // weight tiles (bf16, transposed: [out_dim][k])
    __shared__ __attribute__((aligned(16))) unsigned short w1s[64 * 64]; // W1ext^T
    __shared__ __attribute__((aligned(16))) unsigned short w2s[64 * 64]; // W2ext^T
    __shared__ __attribute__((aligned(16))) unsigned short encN[16 * 32];
    __shared__ __attribute__((aligned(16))) unsigned short encE[16 * 32];
    __shared__ __attribute__((aligned(16))) unsigned short dW1[16 * 32];
    __shared__ __attribute__((aligned(16))) unsigned short dW2[16 * 32];
    __shared__ __attribute__((aligned(16))) unsigned short outW[16 * 64];
    // per-wave activation scratch, XOR-swizzled, row = node (64 ushorts)
    __shared__ __attribute__((aligned(16))) unsigned short sc[WPB][16][64];

    const int tid  = threadIdx.x;
    const int lane = tid & 63;
    const int wave = __builtin_amdgcn_readfirstlane(tid >> 6);
    const int m = lane & 15;          // node-in-tile
    const int q = lane >> 4;          // quad
    const int h3 = m & 7;             // swizzle key
    const int node = blockIdx.x * NPB + wave * 16 + m;   // exact grid, no tail

    // ================= cooperative weight staging =================
    // W1ext^T rows: k 0..49 = W1 state, 50 = W1[50] (t), 51 = b1, 52..63 = 0
    // W2ext^T rows: k 0..49 = W2, 50 = b2, 51..63 = 0   (od >= 50 rows all 0)
#pragma unroll
    for (int it = 0; it < 8; ++it) {
        const int i = tid + it * 256;          // 2048 k-pairs
        const int od = i >> 5;
        const int k2 = (i & 31) * 2;
        float a0 = 0.f, a1 = 0.f, b0 = 0.f, b1 = 0.f;
        if (od < 50) {
            a0 = (k2     < 51) ? ode_w1[k2 * 50 + od]       : 0.f;   // k2 even, never 51
            a1 = (k2 + 1 < 51) ? ode_w1[(k2 + 1) * 50 + od] : ((k2 + 1 == 51) ? ode_b1[od] : 0.f);
            b0 = (k2     < 50) ? ode_w2[k2 * 50 + od]       : ((k2     == 50) ? ode_b2[od] : 0.f);
            b1 = (k2 + 1 < 50) ? ode_w2[(k2 + 1) * 50 + od] : 0.f;   // k2+1 odd, never 50
        }
        *(unsigned*)(w1s + od * 64 + k2) = pk2(a0, a1);
        *(unsigned*)(w2s + od * 64 + k2) = pk2(b0, b1);
    }
    {   // enc/dec 16x32 tiles (k >= 16 zero) — one pass, 256 k-pairs each
        const int mm = tid >> 4;
        const int kp = (tid & 15) * 2;
        const bool rl = (kp < 16);             // kp,kp+1 both <16 iff kp<16 (kp even)
        const float eN0 = rl ? enc_n_w2[kp * 16 + mm] : 0.f;
        const float eN1 = rl ? enc_n_w2[(kp + 1) * 16 + mm] : 0.f;
        const float eE0 = rl ? enc_e_w2[kp * 16 + mm] : 0.f;
        const float eE1 = rl ? enc_e_w2[(kp + 1) * 16 + mm] : 0.f;
        const float d10 = rl ? dec_n_w1[kp * 16 + mm] : 0.f;
        const float d11 = rl ? dec_n_w1[(kp + 1) * 16 + mm] : 0.f;
        const float d20 = rl ? dec_n_w2[kp * 16 + mm] : 0.f;
        const float d21 = rl ? dec_n_w2[(kp + 1) * 16 + mm] : 0.f;
        *(unsigned*)(encN + mm * 32 + kp) = pk2(eN0, eN1);
        *(unsigned*)(encE + mm * 32 + kp) = pk2(eE0, eE1);
        *(unsigned*)(dW1  + mm * 32 + kp) = pk2(d10, d11);
        *(unsigned*)(dW2  + mm * 32 + kp) = pk2(d20, d21);
    }
#pragma unroll
    for (int it = 0; it < 2; ++it) {           // node_out_w^T 16x64 (k >= 50 zero)
        const int i = tid + it * 256;
        const int mm = i >> 5;
        const int kp = (i & 31) * 2;
        const float v0 = (kp     < 50) ? node_out_w[kp * 16 + mm] : 0.f;
        const float v1 = (kp + 1 < 50) ? node_out_w[(kp + 1) * 16 + mm] : 0.f;
        *(unsigned*)(outW + mm * 64 + kp) = pk2(v0, v1);
    }
    __syncthreads();

    // ============ swizzled scratch pointers (hoisted, loop-invariant) ============
    unsigned short* wb = &sc[wave][0][0];
    const unsigned short* rA = wb + m * 64 + ((q ^ h3) * 8);        // k = q*8+j
    const unsigned short* rB = wb + m * 64 + (((4 + q) ^ h3) * 8);  // k = 32+q*8+j
    unsigned short* wct[4];
#pragma unroll
    for (int ct = 0; ct < 4; ++ct)
        wct[ct] = wb + m * 64 + (((2 * ct + (q >> 1)) ^ h3) * 8) + (q & 1) * 4;

    // ============ per-wave fragment loads from staged tiles ============
    short8 w1f[2][4], w2f[2][4];
#pragma unroll
    for (int kt = 0; kt < 2; ++kt)
#pragma unroll
        for (int ct = 0; ct < 4; ++ct) {
            const int od = ct * 16 + m;
            w1f[kt][ct] = *(const short8*)(w1s + od * 64 + kt * 32 + q * 8);
            w2f[kt][ct] = *(const short8*)(w2s + od * 64 + kt * 32 + q * 8);
        }
    const short8 wN = *(const short8*)(encN + m * 32 + q * 8);
    const short8 wE = *(const short8*)(encE + m * 32 + q * 8);
    f32x4 bN, bE;
#pragma unroll
    for (int r = 0; r < 4; ++r) { bN[r] = enc_n_b2[q * 4 + r]; bE[r] = enc_e_b2[q * 4 + r]; }

    const f32x4 zero4 = {0.f, 0.f, 0.f, 0.f};
    f32x4 y[4];

    // ================= encoder (3 MFMAs, bias via C-operand) =================
    *(uint2*)(wct[1]) = make_uint2(0u, 0u);    // dims 16..31 = 0 for K=32 enc GEMMs
    {
        float nf[5];
#pragma unroll
        for (int c = 0; c < 5; ++c) nf[c] = nodes[node * 5 + c];
        float hv[4];
#pragma unroll
        for (int r = 0; r < 4; ++r) {
            const int d = q * 4 + r;
            float s = enc_n_b1[d];
#pragma unroll
            for (int c = 0; c < 5; ++c) s = fmaf(nf[c], enc_n_w1[c * 16 + d], s);
            hv[r] = swishf(s);
        }
        *(uint2*)(wct[0]) = make_uint2(pk2(hv[0], hv[1]), pk2(hv[2], hv[3]));
        short8 fr = *(const short8*)(rA);
        y[0] = __builtin_amdgcn_mfma_f32_16x16x32_bf16(wN, fr, bN, 0, 0, 0);
    }
    {
        const float ev = (node < EE) ? edges[node] : 0.0f;
        float hv[4];
#pragma unroll
        for (int r = 0; r < 4; ++r) {
            const int d = q * 4 + r;
            hv[r] = swishf(fmaf(ev, enc_e_w1[d], enc_e_b1[d]));
        }
        *(uint2*)(wct[0]) = make_uint2(pk2(hv[0], hv[1]), pk2(hv[2], hv[3]));
        short8 fr = *(const short8*)(rA);
        y[1] = __builtin_amdgcn_mfma_f32_16x16x32_bf16(wE, fr, bE, 0, 0, 0);
        if (node == NN - 1) y[1] = zero4;
    }
    {
        const float ev = (node > 0) ? edges[node - 1] : 0.0f;
        float hv[4];
#pragma unroll
        for (int r = 0; r < 4; ++r) {
            const int d = q * 4 + r;
            hv[r] = swishf(fmaf(ev, enc_e_w1[d], enc_e_b1[d]));
        }
        *(uint2*)(wct[0]) = make_uint2(pk2(hv[0], hv[1]), pk2(hv[2], hv[3]));
        short8 fr = *(const short8*)(rA);
        y[2] = __builtin_amdgcn_mfma_f32_16x16x32_bf16(wE, fr, bE, 0, 0, 0);
        if (node == 0) y[2] = zero4;
    }
    y[3] = zero4;
    if (q == 0) { y[3][0] = g[0]; y[3][1] = g[1]; }

    // ============================ RK4 (16 stages) ============================
    const float hh = 1.0f / NSTEPS;
    float t0 = 0.0f;
    f32x4 acc[4];

#pragma unroll
    for (int ct = 0; ct < 4; ++ct) {           // arg0 = y0 (t=0, one=1)
        float x0 = y[ct][0], x1 = y[ct][1], x2 = y[ct][2], x3 = y[ct][3];
        if (ct == 3 && q == 0) { x2 = 0.0f; x3 = 1.0f; }
        *(uint2*)(wct[ct]) = make_uint2(pk2(x0, x1), pk2(x2, x3));
    }

#pragma clang loop unroll(disable)
    for (int stage = 0; stage < 4 * NSTEPS; ++stage) {
        const int s = stage & 3;

        short8 aB0 = *(const short8*)(rA);
        short8 aB1 = *(const short8*)(rB);
        f32x4 hc[4];
#pragma unroll
        for (int ct = 0; ct < 4; ++ct) {
            f32x4 c = __builtin_amdgcn_mfma_f32_16x16x32_bf16(w1f[0][ct], aB0, zero4, 0, 0, 0);
            hc[ct]  = __builtin_amdgcn_mfma_f32_16x16x32_bf16(w1f[1][ct], aB1, c, 0, 0, 0);
        }
#pragma unroll
        for (int ct = 0; ct < 4; ++ct) {       // relu + relayout (col 50 <- 1.0)
            float x0 = fmaxf(hc[ct][0], 0.f), x1 = fmaxf(hc[ct][1], 0.f);
            float x2 = fmaxf(hc[ct][2], 0.f), x3 = fmaxf(hc[ct][3], 0.f);
            if (ct == 3 && q == 0) x2 = 1.0f;
            *(uint2*)(wct[ct]) = make_uint2(pk2(x0, x1), pk2(x2, x3));
        }
        short8 hB0 = *(const short8*)(rA);
        short8 hB1 = *(const short8*)(rB);
        f32x4 kc[4];
#pragma unroll
        for (int ct = 0; ct < 4; ++ct) {
            f32x4 c = __builtin_amdgcn_mfma_f32_16x16x32_bf16(w2f[0][ct], hB0, zero4, 0, 0, 0);
            kc[ct]  = __builtin_amdgcn_mfma_f32_16x16x32_bf16(w2f[1][ct], hB1, c, 0, 0, 0);
        }

        const float ca = (s == 0 || s == 3) ? hh / 6.0f : hh / 3.0f;
        if (s == 0) {
#pragma unroll
            for (int ct = 0; ct < 4; ++ct) acc[ct] = y[ct] + ca * kc[ct];
        } else {
#pragma unroll
            for (int ct = 0; ct < 4; ++ct) acc[ct] = acc[ct] + ca * kc[ct];
        }

        f32x4 av[4];
        float tn;
        if (s < 3) {
            const float cb = (s == 2) ? hh : 0.5f * hh;
#pragma unroll
            for (int ct = 0; ct < 4; ++ct) av[ct] = y[ct] + cb * kc[ct];
            tn = t0 + cb;
        } else {
#pragma unroll
            for (int ct = 0; ct < 4; ++ct) { y[ct] = acc[ct]; av[ct] = acc[ct]; }
            t0 += hh;
            tn = t0;
        }
#pragma unroll
        for (int ct = 0; ct < 4; ++ct) {       // next arg (last iter = y-publish)
            float x0 = av[ct][0], x1 = av[ct][1], x2 = av[ct][2], x3 = av[ct][3];
            if (ct == 3 && q == 0) { x2 = tn; x3 = 1.0f; }
            *(uint2*)(wct[ct]) = make_uint2(pk2(x0, x1), pk2(x2, x3));
        }
    }

    // ========================== decoder (4 MFMAs) ==========================
    const short8 ow0 = *(const short8*)(outW + m * 64 + q * 8);
    const short8 ow1 = *(const short8*)(outW + m * 64 + 32 + q * 8);
    const short8 dw1 = *(const short8*)(dW1 + m * 32 + q * 8);
    const short8 dw2 = *(const short8*)(dW2 + m * 32 + q * 8);
    f32x4 bO, bD1, bD2;
    float w3v[4];
#pragma unroll
    for (int r = 0; r < 4; ++r) {
        bO[r]  = node_out_b[q * 4 + r];
        bD1[r] = dec_n_b1[q * 4 + r];
        bD2[r] = dec_n_b2[q * 4 + r];
        w3v[r] = dec_n_w3[q * 4 + r];
    }

    short8 yA = *(const short8*)(rA);
    short8 yB = *(const short8*)(rB);
    f32x4 nl2 = __builtin_amdgcn_mfma_f32_16x16x32_bf16(ow0, yA, bO, 0, 0, 0);
    nl2       = __builtin_amdgcn_mfma_f32_16x16x32_bf16(ow1, yB, nl2, 0, 0, 0);

    *(uint2*)(wct[0]) = make_uint2(pk2(nl2[0], nl2[1]), pk2(nl2[2], nl2[3]));
    *(uint2*)(wct[1]) = make_uint2(0u, 0u);
    short8 nA = *(const short8*)(rA);
    f32x4 dh = __builtin_amdgcn_mfma_f32_16x16x32_bf16(dw1, nA, bD1, 0, 0, 0);
#pragma unroll
    for (int r = 0; r < 4; ++r) dh[r] = swishf(dh[r]);

    *(uint2*)(wct[0]) = make_uint2(pk2(dh[0], dh[1]), pk2(dh[2], dh[3]));
    short8 dA = *(const short8*)(rA);
    f32x4 dh2 = __builtin_amdgcn_mfma_f32_16x16x32_bf16(dw2, dA, bD2, 0, 0, 0);
#pragma unroll
    for (int r = 0; r < 4; ++r) dh2[r] = swishf(dh2[r]);

    float p = dh2[0] * w3v[0];
    p = fmaf(dh2[1], w3v[1], p);
    p = fmaf(dh2[2], w3v[2], p);
    p = fmaf(dh2[3], w3v[3], p);
    p += __shfl_xor(p, 16);
    p += __shfl_xor(p, 32);
    p += dec_n_b3[0];

    if (q == 0) {
        const float cur_pos = nodes[node * 5 + 0];
        const float c2 = nodes[node * 5 + 2];
        const float c3 = nodes[node * 5 + 3];
        const float cur_vel = nodes[node * 5 + 4];
        const float next_vel = fmaf(p, DTC, cur_vel);
        const float next_pos = fmaf(next_vel, DTC, cur_pos);
        out[node * 6 + 0] = next_pos;
        out[node * 6 + 1] = c2;
        out[node * 6 + 2] = c3;
        out[node * 6 + 3] = cur_vel;
        out[node * 6 + 4] = next_vel;
        out[node * 6 + 5] = p;
    }
}

// second pass: next_edges = diff(next_pos) read back from d_out, plus g_new
__global__ void gnode_edges(const float* __restrict__ out_nodes,
                            float* __restrict__ out,
                            const float* __restrict__ g)
{
    const int e = blockIdx.x * blockDim.x + threadIdx.x;
    if (e < EE) {
        out[NN * 6 + e] = out_nodes[(e + 1) * 6] - out_nodes[e * 6];
    }
    if (e == 0) {
        out[NN * 6 + EE]     = g[0] + 1.0f;
        out[NN * 6 + EE + 1] = g[1];
    }
}

extern "C" void kernel_launch(void* const* d_in, const int* in_sizes, int n_in,
                              void* d_out, int out_size, void* d_ws, size_t ws_size,
                              hipStream_t stream) {
    const float* nodes      = (const float*)d_in[0];
    const float* edges      = (const float*)d_in[1];
    const float* g          = (const float*)d_in[2];
    const float* enc_n_w1   = (const float*)d_in[3];
    const float* enc_n_b1   = (const float*)d_in[4];
    const float* enc_n_w2   = (const float*)d_in[5];
    const float* enc_n_b2   = (const float*)d_in[6];
    const float* enc_e_w1   = (const float*)d_in[7];
    const float* enc_e_b1   = (const float*)d_in[8];
    const float* enc_e_w2   = (const float*)d_in[9];
    const float* enc_e_b2   = (const float*)d_in[10];
    const float* ode_w1     = (const float*)d_in[11];
    const float* ode_b1     = (const float*)d_in[12];
    const float* ode_w2     = (const float*)d_in[13];
    const float* ode_b2     = (const float*)d_in[14];
    const float* node_out_w = (const float*)d_in[15];
    const float* node_out_b = (const float*)d_in[16];
    const float* dec_n_w1   = (const float*)d_in[17];
    const float* dec_n_b1   = (const float*)d_in[18];
    const float* dec_n_w2   = (const float*)d_in[19];
    const float* dec_n_b2   = (const float*)d_in[20];
    const float* dec_n_w3   = (const float*)d_in[21];
    const float* dec_n_b3   = (const float*)d_in[22];
    float* out = (float*)d_out;

    const int blocks = NN / NPB;   // 3125, exact
    gnode_main<<<blocks, 256, 0, stream>>>(
        nodes, edges, g,
        enc_n_w1, enc_n_b1, enc_n_w2, enc_n_b2,
        enc_e_w1, enc_e_b1, enc_e_w2, enc_e_b2,
        ode_w1, ode_b1, ode_w2, ode_b2,
        node_out_w, node_out_b,
        dec_n_w1, dec_n_b1, dec_n_w2, dec_n_b2, dec_n_w3, dec_n_b3,
        out);

    gnode_edges<<<(EE + 255) / 256, 256, 0, stream>>>(out, out, g);
}

// Round 7
// 206.096 us; speedup vs baseline: 13.1816x; 1.0436x over previous
//
#include <hip/hip_runtime.h>
#include <hip/hip_bf16.h>

#define NN 200000
#define EE (NN - 1)
#define NSTEPS 4
#define DTC 0.01f
#define WPB 4
#define NPB 64            // 64 nodes/block; 200000 = 64 * 3125 exactly

typedef __attribute__((ext_vector_type(8))) short short8;
typedef __attribute__((ext_vector_type(4))) float f32x4;

__device__ __forceinline__ unsigned pk2(float lo, float hi) {
    union { __hip_bfloat162 h2; unsigned u; } cv;
    cv.h2 = __float22bfloat162_rn(make_float2(lo, hi));   // v_cvt_pk_bf16_f32
    return cv.u;
}
__device__ __forceinline__ float swishf(float x) { return x / (1.0f + __expf(-x)); }

// R7: LDS arena with sc ALIASED onto w1s. After the barrier-protected pin of
// w1f/w2f into VGPRs, the tile is clobbered by activation scratch, so the
// compiler cannot rematerialize weight frags from LDS inside the stage loop
// (R6: VGPR=84 < 64 frag regs + 32 state -> per-stage ds_read remat, the
// hidden DS load). launch_bounds(256,2) permits the ~140-VGPR live set.
__global__ __launch_bounds__(256, 2)
void gnode_main(const float* __restrict__ nodes,
                const float* __restrict__ edges,
                const float* __restrict__ g,
                const float* __restrict__ enc_n_w1, const float* __restrict__ enc_n_b1,
                const float* __restrict__ enc_n_w2, const float* __restrict__ enc_n_b2,
                const float* __restrict__ enc_e_w1, const float* __restrict__ enc_e_b1,
                const float* __restrict__ enc_e_w2, const float* __restrict__ enc_e_b2,
                const float* __restrict__ ode_w1, const float* __restrict__ ode_b1,
                const float* __restrict__ ode_w2, const float* __restrict__ ode_b2,
                const float* __restrict__ node_out_w, const float* __restrict__ node_out_b,
                const float* __restrict__ dec_n_w1, const float* __restrict__ dec_n_b1,
                const float* __restrict__ dec_n_w2, const float* __restrict__ dec_n_b2,
                const float* __restrict__ dec_n_w3, const float* __restrict__ dec_n_b3,
                float* __restrict__ out)
{
    // arena (ushorts): [0,4096) w1s / later sc ; [4096,8192) w2s ;
    // [8192,8704) encN ; [8704,9216) encE ; [9216,9728) dW1 ;
    // [9728,10240) dW2 ; [10240,11264) outW.   22528 B total.
    __shared__ __attribute__((aligned(16))) unsigned short arena[11264];
    unsigned short* const w1s  = arena;
    unsigned short* const w2s  = arena + 4096;
    unsigned short* const encN = arena + 8192;
    unsigned short* const encE = arena + 8704;
    unsigned short* const dW1  = arena + 9216;
    unsigned short* const dW2  = arena + 9728;
    unsigned short* const outW = arena + 10240;

    const int tid  = threadIdx.x;
    const int lane = tid & 63;
    const int wave = __builtin_amdgcn_readfirstlane(tid >> 6);
    const int m = lane & 15;          // node-in-tile
    const int q = lane >> 4;          // quad
    const int h3 = m & 7;             // swizzle key
    const int node = blockIdx.x * NPB + wave * 16 + m;   // exact grid, no tail

    // ================= cooperative weight staging =================
#pragma unroll
    for (int it = 0; it < 8; ++it) {
        const int i = tid + it * 256;          // 2048 k-pairs
        const int od = i >> 5;
        const int k2 = (i & 31) * 2;
        float a0 = 0.f, a1 = 0.f, b0 = 0.f, b1 = 0.f;
        if (od < 50) {
            a0 = (k2     < 51) ? ode_w1[k2 * 50 + od]       : 0.f;
            a1 = (k2 + 1 < 51) ? ode_w1[(k2 + 1) * 50 + od] : ((k2 + 1 == 51) ? ode_b1[od] : 0.f);
            b0 = (k2     < 50) ? ode_w2[k2 * 50 + od]       : ((k2     == 50) ? ode_b2[od] : 0.f);
            b1 = (k2 + 1 < 50) ? ode_w2[(k2 + 1) * 50 + od] : 0.f;
        }
        *(unsigned*)(w1s + od * 64 + k2) = pk2(a0, a1);
        *(unsigned*)(w2s + od * 64 + k2) = pk2(b0, b1);
    }
    {   // enc/dec 16x32 tiles (k >= 16 zero)
        const int mm = tid >> 4;
        const int kp = (tid & 15) * 2;
        const bool rl = (kp < 16);
        const float eN0 = rl ? enc_n_w2[kp * 16 + mm] : 0.f;
        const float eN1 = rl ? enc_n_w2[(kp + 1) * 16 + mm] : 0.f;
        const float eE0 = rl ? enc_e_w2[kp * 16 + mm] : 0.f;
        const float eE1 = rl ? enc_e_w2[(kp + 1) * 16 + mm] : 0.f;
        const float d10 = rl ? dec_n_w1[kp * 16 + mm] : 0.f;
        const float d11 = rl ? dec_n_w1[(kp + 1) * 16 + mm] : 0.f;
        const float d20 = rl ? dec_n_w2[kp * 16 + mm] : 0.f;
        const float d21 = rl ? dec_n_w2[(kp + 1) * 16 + mm] : 0.f;
        *(unsigned*)(encN + mm * 32 + kp) = pk2(eN0, eN1);
        *(unsigned*)(encE + mm * 32 + kp) = pk2(eE0, eE1);
        *(unsigned*)(dW1  + mm * 32 + kp) = pk2(d10, d11);
        *(unsigned*)(dW2  + mm * 32 + kp) = pk2(d20, d21);
    }
#pragma unroll
    for (int it = 0; it < 2; ++it) {           // node_out_w^T 16x64 (k >= 50 zero)
        const int i = tid + it * 256;
        const int mm = i >> 5;
        const int kp = (i & 31) * 2;
        const float v0 = (kp     < 50) ? node_out_w[kp * 16 + mm] : 0.f;
        const float v1 = (kp + 1 < 50) ? node_out_w[(kp + 1) * 16 + mm] : 0.f;
        *(unsigned*)(outW + mm * 64 + kp) = pk2(v0, v1);
    }
    __syncthreads();

    // ====== pin ODE weight frags in VGPRs (w1s dies after this barrier) ======
    short8 w1f[2][4], w2f[2][4];
#pragma unroll
    for (int kt = 0; kt < 2; ++kt)
#pragma unroll
        for (int ct = 0; ct < 4; ++ct) {
            const int od = ct * 16 + m;
            w1f[kt][ct] = *(const short8*)(w1s + od * 64 + kt * 32 + q * 8);
            w2f[kt][ct] = *(const short8*)(w2s + od * 64 + kt * 32 + q * 8);
        }
    __syncthreads();     // all waves done reading w1s; sc may now clobber it

    // ============ swizzled per-wave scratch (aliases w1s) ============
    unsigned short* const wb = arena + wave * 1024;
    const unsigned short* rA = wb + m * 64 + ((q ^ h3) * 8);        // k = q*8+j
    const unsigned short* rB = wb + m * 64 + (((4 + q) ^ h3) * 8);  // k = 32+q*8+j
    unsigned short* wct[4];
#pragma unroll
    for (int ct = 0; ct < 4; ++ct)
        wct[ct] = wb + m * 64 + (((2 * ct + (q >> 1)) ^ h3) * 8) + (q & 1) * 4;

    const short8 wN = *(const short8*)(encN + m * 32 + q * 8);
    const short8 wE = *(const short8*)(encE + m * 32 + q * 8);
    f32x4 bN, bE;
#pragma unroll
    for (int r = 0; r < 4; ++r) { bN[r] = enc_n_b2[q * 4 + r]; bE[r] = enc_e_b2[q * 4 + r]; }

    const f32x4 zero4 = {0.f, 0.f, 0.f, 0.f};
    f32x4 y[4];

    // ================= encoder (3 MFMAs, bias via C-operand) =================
    *(uint2*)(wct[1]) = make_uint2(0u, 0u);    // dims 16..31 = 0 for K=32 enc GEMMs
    {
        float nf[5];
#pragma unroll
        for (int c = 0; c < 5; ++c) nf[c] = nodes[node * 5 + c];
        float hv[4];
#pragma unroll
        for (int r = 0; r < 4; ++r) {
            const int d = q * 4 + r;
            float s = enc_n_b1[d];
#pragma unroll
            for (int c = 0; c < 5; ++c) s = fmaf(nf[c], enc_n_w1[c * 16 + d], s);
            hv[r] = swishf(s);
        }
        *(uint2*)(wct[0]) = make_uint2(pk2(hv[0], hv[1]), pk2(hv[2], hv[3]));
        short8 fr = *(const short8*)(rA);
        y[0] = __builtin_amdgcn_mfma_f32_16x16x32_bf16(wN, fr, bN, 0, 0, 0);
    }
    {
        const float ev = (node < EE) ? edges[node] : 0.0f;
        float hv[4];
#pragma unroll
        for (int r = 0; r < 4; ++r) {
            const int d = q * 4 + r;
            hv[r] = swishf(fmaf(ev, enc_e_w1[d], enc_e_b1[d]));
        }
        *(uint2*)(wct[0]) = make_uint2(pk2(hv[0], hv[1]), pk2(hv[2], hv[3]));
        short8 fr = *(const short8*)(rA);
        y[1] = __builtin_amdgcn_mfma_f32_16x16x32_bf16(wE, fr, bE, 0, 0, 0);
        if (node == NN - 1) y[1] = zero4;
    }
    {
        const float ev = (node > 0) ? edges[node - 1] : 0.0f;
        float hv[4];
#pragma unroll
        for (int r = 0; r < 4; ++r) {
            const int d = q * 4 + r;
            hv[r] = swishf(fmaf(ev, enc_e_w1[d], enc_e_b1[d]));
        }
        *(uint2*)(wct[0]) = make_uint2(pk2(hv[0], hv[1]), pk2(hv[2], hv[3]));
        short8 fr = *(const short8*)(rA);
        y[2] = __builtin_amdgcn_mfma_f32_16x16x32_bf16(wE, fr, bE, 0, 0, 0);
        if (node == 0) y[2] = zero4;
    }
    y[3] = zero4;
    if (q == 0) { y[3][0] = g[0]; y[3][1] = g[1]; }

    // ============================ RK4 (16 stages) ============================
    const float hh = 1.0f / NSTEPS;
    float t0 = 0.0f;
    f32x4 acc[4];

#pragma unroll
    for (int ct = 0; ct < 4; ++ct) {           // arg0 = y0 (t=0, one=1)
        float x0 = y[ct][0], x1 = y[ct][1], x2 = y[ct][2], x3 = y[ct][3];
        if (ct == 3 && q == 0) { x2 = 0.0f; x3 = 1.0f; }
        *(uint2*)(wct[ct]) = make_uint2(pk2(x0, x1), pk2(x2, x3));
    }

#pragma clang loop unroll(disable)
    for (int stage = 0; stage < 4 * NSTEPS; ++stage) {
        const int s = stage & 3;

        short8 aB0 = *(const short8*)(rA);
        short8 aB1 = *(const short8*)(rB);
        f32x4 hc[4];
#pragma unroll
        for (int ct = 0; ct < 4; ++ct) {
            f32x4 c = __builtin_amdgcn_mfma_f32_16x16x32_bf16(w1f[0][ct], aB0, zero4, 0, 0, 0);
            hc[ct]  = __builtin_amdgcn_mfma_f32_16x16x32_bf16(w1f[1][ct], aB1, c, 0, 0, 0);
        }
#pragma unroll
        for (int ct = 0; ct < 4; ++ct) {       // relu + relayout (col 50 <- 1.0)
            float x0 = fmaxf(hc[ct][0], 0.f), x1 = fmaxf(hc[ct][1], 0.f);
            float x2 = fmaxf(hc[ct][2], 0.f), x3 = fmaxf(hc[ct][3], 0.f);
            if (ct == 3 && q == 0) x2 = 1.0f;
            *(uint2*)(wct[ct]) = make_uint2(pk2(x0, x1), pk2(x2, x3));
        }
        short8 hB0 = *(const short8*)(rA);
        short8 hB1 = *(const short8*)(rB);
        f32x4 kc[4];
#pragma unroll
        for (int ct = 0; ct < 4; ++ct) {
            f32x4 c = __builtin_amdgcn_mfma_f32_16x16x32_bf16(w2f[0][ct], hB0, zero4, 0, 0, 0);
            kc[ct]  = __builtin_amdgcn_mfma_f32_16x16x32_bf16(w2f[1][ct], hB1, c, 0, 0, 0);
        }

        const float ca = (s == 0 || s == 3) ? hh / 6.0f : hh / 3.0f;
        if (s == 0) {
#pragma unroll
            for (int ct = 0; ct < 4; ++ct) acc[ct] = y[ct] + ca * kc[ct];
        } else {
#pragma unroll
            for (int ct = 0; ct < 4; ++ct) acc[ct] = acc[ct] + ca * kc[ct];
        }

        f32x4 av[4];
        float tn;
        if (s < 3) {
            const float cb = (s == 2) ? hh : 0.5f * hh;
#pragma unroll
            for (int ct = 0; ct < 4; ++ct) av[ct] = y[ct] + cb * kc[ct];
            tn = t0 + cb;
        } else {
#pragma unroll
            for (int ct = 0; ct < 4; ++ct) { y[ct] = acc[ct]; av[ct] = acc[ct]; }
            t0 += hh;
            tn = t0;
        }
#pragma unroll
        for (int ct = 0; ct < 4; ++ct) {       // next arg (last iter = y-publish)
            float x0 = av[ct][0], x1 = av[ct][1], x2 = av[ct][2], x3 = av[ct][3];
            if (ct == 3 && q == 0) { x2 = tn; x3 = 1.0f; }
            *(uint2*)(wct[ct]) = make_uint2(pk2(x0, x1), pk2(x2, x3));
        }
    }

    // ========================== decoder (4 MFMAs) ==========================
    const short8 ow0 = *(const short8*)(outW + m * 64 + q * 8);
    const short8 ow1 = *(const short8*)(outW + m * 64 + 32 + q * 8);
    const short8 dw1 = *(const short8*)(dW1 + m * 32 + q * 8);
    const short8 dw2 = *(const short8*)(dW2 + m * 32 + q * 8);
    f32x4 bO, bD1, bD2;
    float w3v[4];
#pragma unroll
    for (int r = 0; r < 4; ++r) {
        bO[r]  = node_out_b[q * 4 + r];
        bD1[r] = dec_n_b1[q * 4 + r];
        bD2[r] = dec_n_b2[q * 4 + r];
        w3v[r] = dec_n_w3[q * 4 + r];
    }

    short8 yA = *(const short8*)(rA);
    short8 yB = *(const short8*)(rB);
    f32x4 nl2 = __builtin_amdgcn_mfma_f32_16x16x32_bf16(ow0, yA, bO, 0, 0, 0);
    nl2       = __builtin_amdgcn_mfma_f32_16x16x32_bf16(ow1, yB, nl2, 0, 0, 0);

    *(uint2*)(wct[0]) = make_uint2(pk2(nl2[0], nl2[1]), pk2(nl2[2], nl2[3]));
    *(uint2*)(wct[1]) = make_uint2(0u, 0u);
    short8 nA = *(const short8*)(rA);
    f32x4 dh = __builtin_amdgcn_mfma_f32_16x16x32_bf16(dw1, nA, bD1, 0, 0, 0);
#pragma unroll
    for (int r = 0; r < 4; ++r) dh[r] = swishf(dh[r]);

    *(uint2*)(wct[0]) = make_uint2(pk2(dh[0], dh[1]), pk2(dh[2], dh[3]));
    short8 dA = *(const short8*)(rA);
    f32x4 dh2 = __builtin_amdgcn_mfma_f32_16x16x32_bf16(dw2, dA, bD2, 0, 0, 0);
#pragma unroll
    for (int r = 0; r < 4; ++r) dh2[r] = swishf(dh2[r]);

    float p = dh2[0] * w3v[0];
    p = fmaf(dh2[1], w3v[1], p);
    p = fmaf(dh2[2], w3v[2], p);
    p = fmaf(dh2[3], w3v[3], p);
    p += __shfl_xor(p, 16);
    p += __shfl_xor(p, 32);
    p += dec_n_b3[0];

    if (q == 0) {
        const float cur_pos = nodes[node * 5 + 0];
        const float c2 = nodes[node * 5 + 2];
        const float c3 = nodes[node * 5 + 3];
        const float cur_vel = nodes[node * 5 + 4];
        const float next_vel = fmaf(p, DTC, cur_vel);
        const float next_pos = fmaf(next_vel, DTC, cur_pos);
        out[node * 6 + 0] = next_pos;
        out[node * 6 + 1] = c2;
        out[node * 6 + 2] = c3;
        out[node * 6 + 3] = cur_vel;
        out[node * 6 + 4] = next_vel;
        out[node * 6 + 5] = p;
    }
}

// second pass: next_edges = diff(next_pos) read back from d_out, plus g_new
__global__ void gnode_edges(const float* __restrict__ out_nodes,
                            float* __restrict__ out,
                            const float* __restrict__ g)
{
    const int e = blockIdx.x * blockDim.x + threadIdx.x;
    if (e < EE) {
        out[NN * 6 + e] = out_nodes[(e + 1) * 6] - out_nodes[e * 6];
    }
    if (e == 0) {
        out[NN * 6 + EE]     = g[0] + 1.0f;
        out[NN * 6 + EE + 1] = g[1];
    }
}

extern "C" void kernel_launch(void* const* d_in, const int* in_sizes, int n_in,
                              void* d_out, int out_size, void* d_ws, size_t ws_size,
                              hipStream_t stream) {
    const float* nodes      = (const float*)d_in[0];
    const float* edges      = (const float*)d_in[1];
    const float* g          = (const float*)d_in[2];
    const float* enc_n_w1   = (const float*)d_in[3];
    const float* enc_n_b1   = (const float*)d_in[4];
    const float* enc_n_w2   = (const float*)d_in[5];
    const float* enc_n_b2   = (const float*)d_in[6];
    const float* enc_e_w1   = (const float*)d_in[7];
    const float* enc_e_b1   = (const float*)d_in[8];
    const float* enc_e_w2   = (const float*)d_in[9];
    const float* enc_e_b2   = (const float*)d_in[10];
    const float* ode_w1     = (const float*)d_in[11];
    const float* ode_b1     = (const float*)d_in[12];
    const float* ode_w2     = (const float*)d_in[13];
    const float* ode_b2     = (const float*)d_in[14];
    const float* node_out_w = (const float*)d_in[15];
    const float* node_out_b = (const float*)d_in[16];
    const float* dec_n_w1   = (const float*)d_in[17];
    const float* dec_n_b1   = (const float*)d_in[18];
    const float* dec_n_w2   = (const float*)d_in[19];
    const float* dec_n_b2   = (const float*)d_in[20];
    const float* dec_n_w3   = (const float*)d_in[21];
    const float* dec_n_b3   = (const float*)d_in[22];
    float* out = (float*)d_out;

    const int blocks = NN / NPB;   // 3125, exact
    gnode_main<<<blocks, 256, 0, stream>>>(
        nodes, edges, g,
        enc_n_w1, enc_n_b1, enc_n_w2, enc_n_b2,
        enc_e_w1, enc_e_b1, enc_e_w2, enc_e_b2,
        ode_w1, ode_b1, ode_w2, ode_b2,
        node_out_w, node_out_b,
        dec_n_w1, dec_n_b1, dec_n_w2, dec_n_b2, dec_n_w3, dec_n_b3,
        out);

    gnode_edges<<<(EE + 255) / 256, 256, 0, stream>>>(out, out, g);
}